// Round 1
// baseline (998.299 us; speedup 1.0000x reference)
//
#include <hip/hip_runtime.h>

// MoE layer: B=4,T=1024,C=1024,H=4096,E=8, top-2 routing, shared expert.
// Sparse formulation: only top-2 experts per token are computed (exact same math
// as the dense reference since non-selected experts get weight 0).
//
// Pipeline (all on `stream`):
//   init -> xconv(bf16) -> 4x transpose+convert weights(bf16 B^T) -> router
//   -> setup(offsets/aux) -> scatter(slot lists) -> GEMM1(relu MLP-in)
//   -> GEMM2(MLP-out) -> combine.
// GEMMs: m97-structure MFMA bf16 128x128 tile, BK=32, global_load_lds width 16.

typedef unsigned short u16;
typedef __bf16 bf16x8 __attribute__((ext_vector_type(8)));
typedef float f32x4 __attribute__((ext_vector_type(4)));

#define NTOK 4096
#define CDIM 1024
#define HDIM 4096
#define NEXP 8
#define SLOTS 13312   // 4096 shared (identity) + 9216 routed capacity (128-aligned segs)
#define NTILES 104    // SLOTS/128

static __device__ __forceinline__ u16 f2bf(float f) {   // round-to-nearest-even
  unsigned u = __float_as_uint(f);
  u += 0x7fffu + ((u >> 16) & 1u);
  return (u16)(u >> 16);
}

static __device__ __forceinline__ void gload16(const void* g, void* l) {
  __builtin_amdgcn_global_load_lds((const __attribute__((address_space(1))) unsigned int*)g,
                                   (__attribute__((address_space(3))) unsigned int*)l,
                                   16, 0, 0);
}

// ---------------- init: zero counters, identity/pad slot map ----------------
__global__ void init_kernel(int* order, int* tile_expert, float* Psum, int* counts, int* cursor) {
  int i = blockIdx.x * 256 + threadIdx.x;      // grid 52*256 = 13312
  if (i < SLOTS) order[i] = (i < NTOK) ? i : -1;
  if (i < NTILES) tile_expert[i] = (i < 32) ? 8 : -1;   // tiles 0..31 = shared expert
  if (i < NEXP) { Psum[i] = 0.f; counts[i] = 0; cursor[i] = 0; }
}

// ---------------- X fp32 -> bf16 ----------------
__global__ void xconv_kernel(const float* __restrict__ X, u16* __restrict__ Xb) {
  int i = blockIdx.x * 256 + threadIdx.x;      // 1M threads, 4 elems each
  float4 v = ((const float4*)X)[i];
  u16 o0 = f2bf(v.x), o1 = f2bf(v.y), o2 = f2bf(v.z), o3 = f2bf(v.w);
  unsigned long long pack = (unsigned long long)o0 | ((unsigned long long)o1 << 16)
                          | ((unsigned long long)o2 << 32) | ((unsigned long long)o3 << 48);
  ((unsigned long long*)Xb)[i] = pack;
}

// ---------------- transpose + convert: src fp32 [b][R][Cc] -> dst bf16 [b][Cc][R] ----------------
__global__ void tconv_kernel(const float* __restrict__ src, u16* __restrict__ dst, int R, int Cc) {
  __shared__ float t[32][33];
  const size_t bofs = (size_t)blockIdx.z * R * Cc;
  src += bofs; dst += bofs;
  int tx = threadIdx.x & 31, ty = threadIdx.x >> 5;   // 32x8
  int r0 = blockIdx.y * 32, c0 = blockIdx.x * 32;
#pragma unroll
  for (int i = 0; i < 32; i += 8)
    t[ty + i][tx] = src[(size_t)(r0 + ty + i) * Cc + c0 + tx];
  __syncthreads();
#pragma unroll
  for (int i = 0; i < 32; i += 8)
    dst[(size_t)(c0 + ty + i) * R + r0 + tx] = f2bf(t[tx][ty + i]);
}

// ---------------- router: 1 wave / token ----------------
__global__ __launch_bounds__(256) void router_kernel(
    const float* __restrict__ X, const float* __restrict__ rw,
    float* __restrict__ w01, int* __restrict__ e01,
    float* __restrict__ Psum, int* __restrict__ counts) {
  int wid = (blockIdx.x * 256 + threadIdx.x) >> 6;   // token, grid 1024 blocks
  int l = threadIdx.x & 63;
  const float* x = X + (size_t)wid * CDIM;
  float s[8] = {0.f,0.f,0.f,0.f,0.f,0.f,0.f,0.f};
#pragma unroll 4
  for (int i = 0; i < 16; ++i) {
    int c = i * 64 + l;
    float xv = x[c];
    const float4* rp = (const float4*)(rw + c * 8);
    float4 r0 = rp[0], r1 = rp[1];
    s[0] += xv * r0.x; s[1] += xv * r0.y; s[2] += xv * r0.z; s[3] += xv * r0.w;
    s[4] += xv * r1.x; s[5] += xv * r1.y; s[6] += xv * r1.z; s[7] += xv * r1.w;
  }
#pragma unroll
  for (int off = 32; off; off >>= 1)
#pragma unroll
    for (int e = 0; e < 8; ++e) s[e] += __shfl_down(s[e], off);
  if (l == 0) {
    float m = s[0];
#pragma unroll
    for (int e = 1; e < 8; ++e) m = fmaxf(m, s[e]);
    float p[8], d = 0.f;
#pragma unroll
    for (int e = 0; e < 8; ++e) { p[e] = expf(s[e] - m); d += p[e]; }
    float inv = 1.f / d;
#pragma unroll
    for (int e = 0; e < 8; ++e) p[e] *= inv;
    int e0 = 0;
#pragma unroll
    for (int e = 1; e < 8; ++e) if (p[e] > p[e0]) e0 = e;   // ties -> lowest idx (jax)
    int e1 = -1;
#pragma unroll
    for (int e = 0; e < 8; ++e) if (e != e0 && (e1 < 0 || p[e] > p[e1])) e1 = e;
    w01[wid * 2] = p[e0]; w01[wid * 2 + 1] = p[e1];
    e01[wid * 2] = e0;    e01[wid * 2 + 1] = e1;
#pragma unroll
    for (int e = 0; e < 8; ++e) atomicAdd(&Psum[e], p[e]);
    atomicAdd(&counts[e0], 1); atomicAdd(&counts[e1], 1);
  }
}

// ---------------- setup: padded per-expert offsets, tile->expert map, aux loss ----------------
__global__ void setup_kernel(const int* __restrict__ counts, const float* __restrict__ Psum,
                             int* __restrict__ roff, int* __restrict__ tile_expert,
                             float* __restrict__ out_aux) {
  if (threadIdx.x == 0 && blockIdx.x == 0) {
    int off = NTOK;                       // routed region starts after shared slots
    for (int e = 0; e < NEXP; ++e) {
      roff[e] = off;
      int nt = (counts[e] + 127) >> 7;
      int t0 = off >> 7;
      for (int i = 0; i < nt; ++i) tile_expert[t0 + i] = e;
      off += nt << 7;
    }
    float a = 0.f;
    for (int e = 0; e < NEXP; ++e)
      a += (counts[e] * (1.f / NTOK)) * (Psum[e] * (1.f / NTOK));
    out_aux[0] = (float)NEXP * a;
  }
}

// ---------------- scatter: token -> slots ----------------
__global__ void scatter_kernel(const int* __restrict__ e01, const int* __restrict__ roff,
                               int* __restrict__ cursor, int* __restrict__ order,
                               int* __restrict__ slot_of) {
  int t = blockIdx.x * 256 + threadIdx.x;   // grid 16 blocks
  if (t >= NTOK) return;
#pragma unroll
  for (int k = 0; k < 2; ++k) {
    int e = e01[t * 2 + k];
    int pos = atomicAdd(&cursor[e], 1);
    int slot = roff[e] + pos;
    order[slot] = t;
    slot_of[t * 2 + k] = slot;
  }
}

// ---------------- GEMM1: hidden = relu(A @ W1^T + b1), A rows via order[], out bf16 ----------------
__global__ __launch_bounds__(256) void gemm_h_kernel(
    const u16* __restrict__ Xb, const u16* __restrict__ W1t, const u16* __restrict__ RW1t,
    const float* __restrict__ sh_b1, const float* __restrict__ rt_b1,
    const int* __restrict__ tile_expert, const int* __restrict__ order,
    u16* __restrict__ Hu) {
  int e = tile_expert[blockIdx.y];
  if (e < 0) return;
  const u16* Bw = (e == 8) ? W1t : RW1t + (size_t)e * HDIM * CDIM;
  const float* bias = (e == 8) ? sh_b1 : rt_b1 + e * HDIM;

  __shared__ u16 As[128 * 32];
  __shared__ u16 Bs[128 * 32];

  const int tid = threadIdx.x;
  const int l = tid & 63, w = tid >> 6;
  const int wm = w >> 1, wn = w & 1;
  const int fr = l & 15, fq = l >> 4;
  const int m0 = blockIdx.y * 128, n0 = blockIdx.x * 128;
  const int sr = tid >> 2;          // staging row within 64-row round
  const int sk = (tid & 3) * 8;     // staging k offset (elems)

  int tok0 = order[m0 + sr];      if (tok0 < 0) tok0 = 0;
  int tok1 = order[m0 + 64 + sr]; if (tok1 < 0) tok1 = 0;
  const u16* aS0 = Xb + (size_t)tok0 * CDIM + sk;
  const u16* aS1 = Xb + (size_t)tok1 * CDIM + sk;
  const u16* bS0 = Bw + (size_t)(n0 + sr) * CDIM + sk;
  const u16* bS1 = Bw + (size_t)(n0 + 64 + sr) * CDIM + sk;
  u16* aD0 = As + w * 512;  u16* aD1 = As + 2048 + w * 512;   // wave-uniform LDS bases
  u16* bD0 = Bs + w * 512;  u16* bD1 = Bs + 2048 + w * 512;

  f32x4 acc[4][4] = {};
  for (int kt = 0; kt < CDIM / 32; ++kt) {
    gload16(aS0, aD0); gload16(aS1, aD1);
    gload16(bS0, bD0); gload16(bS1, bD1);
    aS0 += 32; aS1 += 32; bS0 += 32; bS1 += 32;
    __syncthreads();
    bf16x8 af[4], bv[4];
#pragma unroll
    for (int i = 0; i < 4; ++i) af[i] = *(const bf16x8*)&As[(wm * 64 + i * 16 + fr) * 32 + fq * 8];
#pragma unroll
    for (int j = 0; j < 4; ++j) bv[j] = *(const bf16x8*)&Bs[(wn * 64 + j * 16 + fr) * 32 + fq * 8];
#pragma unroll
    for (int i = 0; i < 4; ++i)
#pragma unroll
      for (int j = 0; j < 4; ++j)
        acc[i][j] = __builtin_amdgcn_mfma_f32_16x16x32_bf16(af[i], bv[j], acc[i][j], 0, 0, 0);
    __syncthreads();
  }

  const size_t mb = m0 + wm * 64;
  const int nb = n0 + wn * 64;
#pragma unroll
  for (int j = 0; j < 4; ++j) {
    const int n_g = nb + j * 16 + fr;
    const float bvf = bias[n_g];
#pragma unroll
    for (int i = 0; i < 4; ++i)
#pragma unroll
      for (int r = 0; r < 4; ++r) {
        float v = acc[i][j][r] + bvf;
        v = fmaxf(v, 0.0f);
        Hu[(mb + i * 16 + fq * 4 + r) * (size_t)HDIM + n_g] = f2bf(v);
      }
  }
}

// ---------------- GEMM2: Yu = Hu @ W2^T + b2 (fp32 out) ----------------
__global__ __launch_bounds__(256) void gemm_o_kernel(
    const u16* __restrict__ Hu, const u16* __restrict__ W2t, const u16* __restrict__ RW2t,
    const float* __restrict__ sh_b2, const float* __restrict__ rt_b2,
    const int* __restrict__ tile_expert,
    float* __restrict__ Yu) {
  int e = tile_expert[blockIdx.y];
  if (e < 0) return;
  const u16* Bw = (e == 8) ? W2t : RW2t + (size_t)e * CDIM * HDIM;
  const float* bias = (e == 8) ? sh_b2 : rt_b2 + e * CDIM;

  __shared__ u16 As[128 * 32];
  __shared__ u16 Bs[128 * 32];

  const int tid = threadIdx.x;
  const int l = tid & 63, w = tid >> 6;
  const int wm = w >> 1, wn = w & 1;
  const int fr = l & 15, fq = l >> 4;
  const int m0 = blockIdx.y * 128, n0 = blockIdx.x * 128;
  const int sr = tid >> 2;
  const int sk = (tid & 3) * 8;

  const u16* aS0 = Hu + (size_t)(m0 + sr) * HDIM + sk;
  const u16* aS1 = Hu + (size_t)(m0 + 64 + sr) * HDIM + sk;
  const u16* bS0 = Bw + (size_t)(n0 + sr) * HDIM + sk;
  const u16* bS1 = Bw + (size_t)(n0 + 64 + sr) * HDIM + sk;
  u16* aD0 = As + w * 512;  u16* aD1 = As + 2048 + w * 512;
  u16* bD0 = Bs + w * 512;  u16* bD1 = Bs + 2048 + w * 512;

  f32x4 acc[4][4] = {};
  for (int kt = 0; kt < HDIM / 32; ++kt) {
    gload16(aS0, aD0); gload16(aS1, aD1);
    gload16(bS0, bD0); gload16(bS1, bD1);
    aS0 += 32; aS1 += 32; bS0 += 32; bS1 += 32;
    __syncthreads();
    bf16x8 af[4], bv[4];
#pragma unroll
    for (int i = 0; i < 4; ++i) af[i] = *(const bf16x8*)&As[(wm * 64 + i * 16 + fr) * 32 + fq * 8];
#pragma unroll
    for (int j = 0; j < 4; ++j) bv[j] = *(const bf16x8*)&Bs[(wn * 64 + j * 16 + fr) * 32 + fq * 8];
#pragma unroll
    for (int i = 0; i < 4; ++i)
#pragma unroll
      for (int j = 0; j < 4; ++j)
        acc[i][j] = __builtin_amdgcn_mfma_f32_16x16x32_bf16(af[i], bv[j], acc[i][j], 0, 0, 0);
    __syncthreads();
  }

  const size_t mb = m0 + wm * 64;
  const int nb = n0 + wn * 64;
#pragma unroll
  for (int j = 0; j < 4; ++j) {
    const int n_g = nb + j * 16 + fr;
    const float bvf = bias[n_g];
#pragma unroll
    for (int i = 0; i < 4; ++i)
#pragma unroll
      for (int r = 0; r < 4; ++r)
        Yu[(mb + i * 16 + fq * 4 + r) * (size_t)CDIM + n_g] = acc[i][j][r] + bvf;
  }
}

// ---------------- combine: out = shared + w0*expert0 + w1*expert1 ----------------
__global__ void combine_kernel(const float* __restrict__ Yu, const float* __restrict__ w01,
                               const int* __restrict__ slot_of, float* __restrict__ out) {
  int gid = blockIdx.x * 256 + threadIdx.x;   // 4096 blocks; 256 float4 per token row
  int t = gid >> 8;
  int c4 = gid & 255;
  int s0 = slot_of[t * 2], s1 = slot_of[t * 2 + 1];
  float wq0 = w01[t * 2], wq1 = w01[t * 2 + 1];
  float4 a  = ((const float4*)(Yu + (size_t)t  * CDIM))[c4];
  float4 b0 = ((const float4*)(Yu + (size_t)s0 * CDIM))[c4];
  float4 b1 = ((const float4*)(Yu + (size_t)s1 * CDIM))[c4];
  float4 rv;
  rv.x = a.x + wq0 * b0.x + wq1 * b1.x;
  rv.y = a.y + wq0 * b0.y + wq1 * b1.y;
  rv.z = a.z + wq0 * b0.z + wq1 * b1.z;
  rv.w = a.w + wq0 * b0.w + wq1 * b1.w;
  ((float4*)out)[gid] = rv;
}

extern "C" void kernel_launch(void* const* d_in, const int* in_sizes, int n_in,
                              void* d_out, int out_size, void* d_ws, size_t ws_size,
                              hipStream_t stream) {
  const float* X        = (const float*)d_in[0];   // [4096,1024]
  const float* router_w = (const float*)d_in[1];   // [1024,8]
  const float* sh_w1    = (const float*)d_in[2];   // [1024,4096]
  const float* sh_b1    = (const float*)d_in[3];   // [4096]
  const float* sh_w2    = (const float*)d_in[4];   // [4096,1024]
  const float* sh_b2    = (const float*)d_in[5];   // [1024]
  const float* rt_w1    = (const float*)d_in[6];   // [8,1024,4096]
  const float* rt_b1    = (const float*)d_in[7];   // [8,4096]
  const float* rt_w2    = (const float*)d_in[8];   // [8,4096,1024]
  const float* rt_b2    = (const float*)d_in[9];   // [8,1024]
  float* out = (float*)d_out;

  // ---- workspace layout ----
  char* p = (char*)d_ws;
  auto take = [&](size_t bytes) { char* q = p; p += (bytes + 255) & ~(size_t)255; return q; };
  u16*  Xb   = (u16*)take((size_t)NTOK * CDIM * 2);        //   8 MB
  u16*  W1t  = (u16*)take((size_t)HDIM * CDIM * 2);        //   8 MB  sh_w1^T [H][C]
  u16*  W2t  = (u16*)take((size_t)CDIM * HDIM * 2);        //   8 MB  sh_w2^T [C][H]
  u16*  RW1t = (u16*)take((size_t)NEXP * HDIM * CDIM * 2); //  64 MB  [E][H][C]
  u16*  RW2t = (u16*)take((size_t)NEXP * CDIM * HDIM * 2); //  64 MB  [E][C][H]
  u16*  Hu   = (u16*)take((size_t)SLOTS * HDIM * 2);       // 104 MB
  float* Yu  = (float*)take((size_t)SLOTS * CDIM * 4);     //  52 MB
  float* w01 = (float*)take((size_t)NTOK * 2 * 4);
  int*  e01  = (int*)take((size_t)NTOK * 2 * 4);
  int*  slot_of = (int*)take((size_t)NTOK * 2 * 4);
  int*  order   = (int*)take((size_t)SLOTS * 4);
  int*  tile_expert = (int*)take((size_t)NTILES * 4);
  float* Psum = (float*)take(256);
  int*  counts = (int*)take(256);
  int*  cursor = (int*)take(256);
  int*  roff   = (int*)take(256);
  size_t need = (size_t)(p - (char*)d_ws);
  if (ws_size < need) return;  // insufficient scratch -> fail visibly (poisoned out)

  // ---- pipeline ----
  init_kernel<<<52, 256, 0, stream>>>(order, tile_expert, Psum, counts, cursor);
  xconv_kernel<<<(NTOK * CDIM / 4) / 256, 256, 0, stream>>>(X, Xb);
  tconv_kernel<<<dim3(HDIM / 32, CDIM / 32, 1), 256, 0, stream>>>(sh_w1, W1t, CDIM, HDIM);
  tconv_kernel<<<dim3(CDIM / 32, HDIM / 32, 1), 256, 0, stream>>>(sh_w2, W2t, HDIM, CDIM);
  tconv_kernel<<<dim3(HDIM / 32, CDIM / 32, NEXP), 256, 0, stream>>>(rt_w1, RW1t, CDIM, HDIM);
  tconv_kernel<<<dim3(CDIM / 32, HDIM / 32, NEXP), 256, 0, stream>>>(rt_w2, RW2t, HDIM, CDIM);
  router_kernel<<<NTOK / 4, 256, 0, stream>>>(X, router_w, w01, e01, Psum, counts);
  setup_kernel<<<1, 64, 0, stream>>>(counts, Psum, roff, tile_expert, out + (size_t)NTOK * CDIM);
  scatter_kernel<<<NTOK / 256, 256, 0, stream>>>(e01, roff, cursor, order, slot_of);
  gemm_h_kernel<<<dim3(HDIM / 128, NTILES), 256, 0, stream>>>(
      Xb, W1t, RW1t, sh_b1, rt_b1, tile_expert, order, Hu);
  gemm_o_kernel<<<dim3(CDIM / 128, NTILES), 256, 0, stream>>>(
      Hu, W2t, RW2t, sh_b2, rt_b2, tile_expert, Yu);
  combine_kernel<<<(NTOK * CDIM / 4) / 256, 256, 0, stream>>>(Yu, w01, slot_of, out);
}

// Round 2
// 568.103 us; speedup vs baseline: 1.7573x; 1.7573x over previous
//
#include <hip/hip_runtime.h>

// MoE layer: B=4,T=1024,C=1024,H=4096,E=8, top-2 routing, shared expert.
// Sparse formulation: only top-2 experts per token are computed (exact same math
// as the dense reference since non-selected experts get weight 0).
//
// R2: removed global-atomic contention (router was 425us = 43% of runtime with
// 41K same-address device atomics). Router now does block-local LDS reduction
// + per-block partials; setup reduces partials in parallel; scatter uses
// block-aggregated cursor updates (128 global atomics total).

typedef unsigned short u16;
typedef __bf16 bf16x8 __attribute__((ext_vector_type(8)));
typedef float f32x4 __attribute__((ext_vector_type(4)));

#define NTOK 4096
#define CDIM 1024
#define HDIM 4096
#define NEXP 8
#define SLOTS 13312   // 4096 shared (identity) + 9216 routed capacity (128-aligned segs)
#define NTILES 104    // SLOTS/128
#define RBLK 1024     // router grid (4 tokens/block)

static __device__ __forceinline__ u16 f2bf(float f) {   // round-to-nearest-even
  unsigned u = __float_as_uint(f);
  u += 0x7fffu + ((u >> 16) & 1u);
  return (u16)(u >> 16);
}

static __device__ __forceinline__ void gload16(const void* g, void* l) {
  __builtin_amdgcn_global_load_lds((const __attribute__((address_space(1))) unsigned int*)g,
                                   (__attribute__((address_space(3))) unsigned int*)l,
                                   16, 0, 0);
}

// ---------------- init: zero cursor, identity/pad slot map ----------------
__global__ void init_kernel(int* order, int* tile_expert, int* cursor) {
  int i = blockIdx.x * 256 + threadIdx.x;      // grid 52*256 = 13312
  if (i < SLOTS) order[i] = (i < NTOK) ? i : -1;
  if (i < NTILES) tile_expert[i] = (i < 32) ? 8 : -1;   // tiles 0..31 = shared expert
  if (i < NEXP) cursor[i] = 0;
}

// ---------------- X fp32 -> bf16 ----------------
__global__ void xconv_kernel(const float* __restrict__ X, u16* __restrict__ Xb) {
  int i = blockIdx.x * 256 + threadIdx.x;      // 1M threads, 4 elems each
  float4 v = ((const float4*)X)[i];
  u16 o0 = f2bf(v.x), o1 = f2bf(v.y), o2 = f2bf(v.z), o3 = f2bf(v.w);
  unsigned long long pack = (unsigned long long)o0 | ((unsigned long long)o1 << 16)
                          | ((unsigned long long)o2 << 32) | ((unsigned long long)o3 << 48);
  ((unsigned long long*)Xb)[i] = pack;
}

// ---------------- transpose + convert: src fp32 [b][R][Cc] -> dst bf16 [b][Cc][R] ----------------
__global__ void tconv_kernel(const float* __restrict__ src, u16* __restrict__ dst, int R, int Cc) {
  __shared__ float t[32][33];
  const size_t bofs = (size_t)blockIdx.z * R * Cc;
  src += bofs; dst += bofs;
  int tx = threadIdx.x & 31, ty = threadIdx.x >> 5;   // 32x8
  int r0 = blockIdx.y * 32, c0 = blockIdx.x * 32;
#pragma unroll
  for (int i = 0; i < 32; i += 8)
    t[ty + i][tx] = src[(size_t)(r0 + ty + i) * Cc + c0 + tx];
  __syncthreads();
#pragma unroll
  for (int i = 0; i < 32; i += 8)
    dst[(size_t)(c0 + ty + i) * R + r0 + tx] = f2bf(t[tx][ty + i]);
}

// ---------------- router: 1 wave/token, block-local reduction, NO global atomics ----------------
__global__ __launch_bounds__(256) void router_kernel(
    const float* __restrict__ X, const float* __restrict__ rw,
    float* __restrict__ w01, int* __restrict__ e01,
    float* __restrict__ pP, int* __restrict__ pC) {
  __shared__ float wP[4][8];
  __shared__ int wE[4][2];
  const int tid = threadIdx.x;
  const int w = tid >> 6, l = tid & 63;
  const int wid = blockIdx.x * 4 + w;   // token
  const float* x = X + (size_t)wid * CDIM;
  float s[8] = {0.f,0.f,0.f,0.f,0.f,0.f,0.f,0.f};
#pragma unroll 4
  for (int i = 0; i < 16; ++i) {
    int c = i * 64 + l;
    float xv = x[c];
    const float4* rp = (const float4*)(rw + c * 8);
    float4 r0 = rp[0], r1 = rp[1];
    s[0] += xv * r0.x; s[1] += xv * r0.y; s[2] += xv * r0.z; s[3] += xv * r0.w;
    s[4] += xv * r1.x; s[5] += xv * r1.y; s[6] += xv * r1.z; s[7] += xv * r1.w;
  }
#pragma unroll
  for (int off = 32; off; off >>= 1)
#pragma unroll
    for (int e = 0; e < 8; ++e) s[e] += __shfl_down(s[e], off);
  if (l == 0) {
    float m = s[0];
#pragma unroll
    for (int e = 1; e < 8; ++e) m = fmaxf(m, s[e]);
    float p[8], d = 0.f;
#pragma unroll
    for (int e = 0; e < 8; ++e) { p[e] = expf(s[e] - m); d += p[e]; }
    float inv = 1.f / d;
#pragma unroll
    for (int e = 0; e < 8; ++e) p[e] *= inv;
    int e0 = 0;
#pragma unroll
    for (int e = 1; e < 8; ++e) if (p[e] > p[e0]) e0 = e;   // ties -> lowest idx (jax)
    int e1 = -1;
#pragma unroll
    for (int e = 0; e < 8; ++e) if (e != e0 && (e1 < 0 || p[e] > p[e1])) e1 = e;
    w01[wid * 2] = p[e0]; w01[wid * 2 + 1] = p[e1];
    e01[wid * 2] = e0;    e01[wid * 2 + 1] = e1;
#pragma unroll
    for (int e = 0; e < 8; ++e) wP[w][e] = p[e];
    wE[w][0] = e0; wE[w][1] = e1;
  }
  __syncthreads();
  if (tid < 8) {
    pP[blockIdx.x * 8 + tid] = wP[0][tid] + wP[1][tid] + wP[2][tid] + wP[3][tid];
    int c = 0;
#pragma unroll
    for (int v = 0; v < 4; ++v) c += (wE[v][0] == tid) + (wE[v][1] == tid);
    pC[blockIdx.x * 8 + tid] = c;
  }
}

// ---------------- setup: reduce partials, offsets, tile map, aux loss ----------------
__global__ __launch_bounds__(256) void setup_kernel(
    const float* __restrict__ pP, const int* __restrict__ pC,
    int* __restrict__ roff, int* __restrict__ tile_expert, float* __restrict__ out_aux) {
  __shared__ float sP[32][8];
  __shared__ int   sC[32][8];
  const int tid = threadIdx.x;
  const int e = tid & 7, g = tid >> 3;   // 32 groups x 8 experts
  float fs = 0.f; int cs = 0;
  for (int b = g; b < RBLK; b += 32) { fs += pP[b * 8 + e]; cs += pC[b * 8 + e]; }
  sP[g][e] = fs; sC[g][e] = cs;
  __syncthreads();
  if (tid == 0) {
    float P[8]; int C[8];
    for (int e2 = 0; e2 < 8; ++e2) {
      float f2 = 0.f; int c2 = 0;
      for (int g2 = 0; g2 < 32; ++g2) { f2 += sP[g2][e2]; c2 += sC[g2][e2]; }
      P[e2] = f2; C[e2] = c2;
    }
    int off = NTOK;
    float a = 0.f;
    for (int e2 = 0; e2 < NEXP; ++e2) {
      roff[e2] = off;
      int nt = (C[e2] + 127) >> 7;
      int t0 = off >> 7;
      for (int i = 0; i < nt; ++i) tile_expert[t0 + i] = e2;
      off += nt << 7;
      a += (C[e2] * (1.f / NTOK)) * (P[e2] * (1.f / NTOK));
    }
    out_aux[0] = (float)NEXP * a;
  }
}

// ---------------- scatter: token -> slots, block-aggregated cursor ----------------
__global__ __launch_bounds__(256) void scatter_kernel(
    const int* __restrict__ e01, const int* __restrict__ roff,
    int* __restrict__ cursor, int* __restrict__ order, int* __restrict__ slot_of) {
  __shared__ int cnt_l[8];
  __shared__ int base_l[8];
  const int tid = threadIdx.x;
  const int t = blockIdx.x * 256 + tid;   // grid 16 blocks
  if (tid < 8) cnt_l[tid] = 0;
  __syncthreads();
  int e0 = e01[t * 2], e1 = e01[t * 2 + 1];
  int p0 = atomicAdd(&cnt_l[e0], 1);      // LDS atomics (fast, per-CU)
  int p1 = atomicAdd(&cnt_l[e1], 1);
  __syncthreads();
  if (tid < 8) base_l[tid] = atomicAdd(&cursor[tid], cnt_l[tid]);  // 8 global atomics/block
  __syncthreads();
  int s0 = roff[e0] + base_l[e0] + p0;
  int s1 = roff[e1] + base_l[e1] + p1;
  order[s0] = t; order[s1] = t;
  slot_of[t * 2] = s0; slot_of[t * 2 + 1] = s1;
}

// ---------------- GEMM1: hidden = relu(A @ W1^T + b1), A rows via order[], out bf16 ----------------
__global__ __launch_bounds__(256) void gemm_h_kernel(
    const u16* __restrict__ Xb, const u16* __restrict__ W1t, const u16* __restrict__ RW1t,
    const float* __restrict__ sh_b1, const float* __restrict__ rt_b1,
    const int* __restrict__ tile_expert, const int* __restrict__ order,
    u16* __restrict__ Hu) {
  int e = tile_expert[blockIdx.y];
  if (e < 0) return;
  const u16* Bw = (e == 8) ? W1t : RW1t + (size_t)e * HDIM * CDIM;
  const float* bias = (e == 8) ? sh_b1 : rt_b1 + e * HDIM;

  __shared__ u16 As[128 * 32];
  __shared__ u16 Bs[128 * 32];

  const int tid = threadIdx.x;
  const int l = tid & 63, w = tid >> 6;
  const int wm = w >> 1, wn = w & 1;
  const int fr = l & 15, fq = l >> 4;
  const int m0 = blockIdx.y * 128, n0 = blockIdx.x * 128;
  const int sr = tid >> 2;          // staging row within 64-row round
  const int sk = (tid & 3) * 8;     // staging k offset (elems)

  int tok0 = order[m0 + sr];      if (tok0 < 0) tok0 = 0;
  int tok1 = order[m0 + 64 + sr]; if (tok1 < 0) tok1 = 0;
  const u16* aS0 = Xb + (size_t)tok0 * CDIM + sk;
  const u16* aS1 = Xb + (size_t)tok1 * CDIM + sk;
  const u16* bS0 = Bw + (size_t)(n0 + sr) * CDIM + sk;
  const u16* bS1 = Bw + (size_t)(n0 + 64 + sr) * CDIM + sk;
  u16* aD0 = As + w * 512;  u16* aD1 = As + 2048 + w * 512;   // wave-uniform LDS bases
  u16* bD0 = Bs + w * 512;  u16* bD1 = Bs + 2048 + w * 512;

  f32x4 acc[4][4] = {};
  for (int kt = 0; kt < CDIM / 32; ++kt) {
    gload16(aS0, aD0); gload16(aS1, aD1);
    gload16(bS0, bD0); gload16(bS1, bD1);
    aS0 += 32; aS1 += 32; bS0 += 32; bS1 += 32;
    __syncthreads();
    bf16x8 af[4], bv[4];
#pragma unroll
    for (int i = 0; i < 4; ++i) af[i] = *(const bf16x8*)&As[(wm * 64 + i * 16 + fr) * 32 + fq * 8];
#pragma unroll
    for (int j = 0; j < 4; ++j) bv[j] = *(const bf16x8*)&Bs[(wn * 64 + j * 16 + fr) * 32 + fq * 8];
#pragma unroll
    for (int i = 0; i < 4; ++i)
#pragma unroll
      for (int j = 0; j < 4; ++j)
        acc[i][j] = __builtin_amdgcn_mfma_f32_16x16x32_bf16(af[i], bv[j], acc[i][j], 0, 0, 0);
    __syncthreads();
  }

  const size_t mb = m0 + wm * 64;
  const int nb = n0 + wn * 64;
#pragma unroll
  for (int j = 0; j < 4; ++j) {
    const int n_g = nb + j * 16 + fr;
    const float bvf = bias[n_g];
#pragma unroll
    for (int i = 0; i < 4; ++i)
#pragma unroll
      for (int r = 0; r < 4; ++r) {
        float v = acc[i][j][r] + bvf;
        v = fmaxf(v, 0.0f);
        Hu[(mb + i * 16 + fq * 4 + r) * (size_t)HDIM + n_g] = f2bf(v);
      }
  }
}

// ---------------- GEMM2: Yu = Hu @ W2^T + b2 (fp32 out) ----------------
__global__ __launch_bounds__(256) void gemm_o_kernel(
    const u16* __restrict__ Hu, const u16* __restrict__ W2t, const u16* __restrict__ RW2t,
    const float* __restrict__ sh_b2, const float* __restrict__ rt_b2,
    const int* __restrict__ tile_expert,
    float* __restrict__ Yu) {
  int e = tile_expert[blockIdx.y];
  if (e < 0) return;
  const u16* Bw = (e == 8) ? W2t : RW2t + (size_t)e * CDIM * HDIM;
  const float* bias = (e == 8) ? sh_b2 : rt_b2 + e * CDIM;

  __shared__ u16 As[128 * 32];
  __shared__ u16 Bs[128 * 32];

  const int tid = threadIdx.x;
  const int l = tid & 63, w = tid >> 6;
  const int wm = w >> 1, wn = w & 1;
  const int fr = l & 15, fq = l >> 4;
  const int m0 = blockIdx.y * 128, n0 = blockIdx.x * 128;
  const int sr = tid >> 2;
  const int sk = (tid & 3) * 8;

  const u16* aS0 = Hu + (size_t)(m0 + sr) * HDIM + sk;
  const u16* aS1 = Hu + (size_t)(m0 + 64 + sr) * HDIM + sk;
  const u16* bS0 = Bw + (size_t)(n0 + sr) * HDIM + sk;
  const u16* bS1 = Bw + (size_t)(n0 + 64 + sr) * HDIM + sk;
  u16* aD0 = As + w * 512;  u16* aD1 = As + 2048 + w * 512;
  u16* bD0 = Bs + w * 512;  u16* bD1 = Bs + 2048 + w * 512;

  f32x4 acc[4][4] = {};
  for (int kt = 0; kt < HDIM / 32; ++kt) {
    gload16(aS0, aD0); gload16(aS1, aD1);
    gload16(bS0, bD0); gload16(bS1, bD1);
    aS0 += 32; aS1 += 32; bS0 += 32; bS1 += 32;
    __syncthreads();
    bf16x8 af[4], bv[4];
#pragma unroll
    for (int i = 0; i < 4; ++i) af[i] = *(const bf16x8*)&As[(wm * 64 + i * 16 + fr) * 32 + fq * 8];
#pragma unroll
    for (int j = 0; j < 4; ++j) bv[j] = *(const bf16x8*)&Bs[(wn * 64 + j * 16 + fr) * 32 + fq * 8];
#pragma unroll
    for (int i = 0; i < 4; ++i)
#pragma unroll
      for (int j = 0; j < 4; ++j)
        acc[i][j] = __builtin_amdgcn_mfma_f32_16x16x32_bf16(af[i], bv[j], acc[i][j], 0, 0, 0);
    __syncthreads();
  }

  const size_t mb = m0 + wm * 64;
  const int nb = n0 + wn * 64;
#pragma unroll
  for (int j = 0; j < 4; ++j) {
    const int n_g = nb + j * 16 + fr;
    const float bvf = bias[n_g];
#pragma unroll
    for (int i = 0; i < 4; ++i)
#pragma unroll
      for (int r = 0; r < 4; ++r)
        Yu[(mb + i * 16 + fq * 4 + r) * (size_t)CDIM + n_g] = acc[i][j][r] + bvf;
  }
}

// ---------------- combine: out = shared + w0*expert0 + w1*expert1 ----------------
__global__ void combine_kernel(const float* __restrict__ Yu, const float* __restrict__ w01,
                               const int* __restrict__ slot_of, float* __restrict__ out) {
  int gid = blockIdx.x * 256 + threadIdx.x;   // 4096 blocks; 256 float4 per token row
  int t = gid >> 8;
  int c4 = gid & 255;
  int s0 = slot_of[t * 2], s1 = slot_of[t * 2 + 1];
  float wq0 = w01[t * 2], wq1 = w01[t * 2 + 1];
  float4 a  = ((const float4*)(Yu + (size_t)t  * CDIM))[c4];
  float4 b0 = ((const float4*)(Yu + (size_t)s0 * CDIM))[c4];
  float4 b1 = ((const float4*)(Yu + (size_t)s1 * CDIM))[c4];
  float4 rv;
  rv.x = a.x + wq0 * b0.x + wq1 * b1.x;
  rv.y = a.y + wq0 * b0.y + wq1 * b1.y;
  rv.z = a.z + wq0 * b0.z + wq1 * b1.z;
  rv.w = a.w + wq0 * b0.w + wq1 * b1.w;
  ((float4*)out)[gid] = rv;
}

extern "C" void kernel_launch(void* const* d_in, const int* in_sizes, int n_in,
                              void* d_out, int out_size, void* d_ws, size_t ws_size,
                              hipStream_t stream) {
  const float* X        = (const float*)d_in[0];   // [4096,1024]
  const float* router_w = (const float*)d_in[1];   // [1024,8]
  const float* sh_w1    = (const float*)d_in[2];   // [1024,4096]
  const float* sh_b1    = (const float*)d_in[3];   // [4096]
  const float* sh_w2    = (const float*)d_in[4];   // [4096,1024]
  const float* sh_b2    = (const float*)d_in[5];   // [1024]
  const float* rt_w1    = (const float*)d_in[6];   // [8,1024,4096]
  const float* rt_b1    = (const float*)d_in[7];   // [8,4096]
  const float* rt_w2    = (const float*)d_in[8];   // [8,4096,1024]
  const float* rt_b2    = (const float*)d_in[9];   // [8,1024]
  float* out = (float*)d_out;

  // ---- workspace layout ----
  char* p = (char*)d_ws;
  auto take = [&](size_t bytes) { char* q = p; p += (bytes + 255) & ~(size_t)255; return q; };
  u16*  Xb   = (u16*)take((size_t)NTOK * CDIM * 2);        //   8 MB
  u16*  W1t  = (u16*)take((size_t)HDIM * CDIM * 2);        //   8 MB  sh_w1^T [H][C]
  u16*  W2t  = (u16*)take((size_t)CDIM * HDIM * 2);        //   8 MB  sh_w2^T [C][H]
  u16*  RW1t = (u16*)take((size_t)NEXP * HDIM * CDIM * 2); //  64 MB  [E][H][C]
  u16*  RW2t = (u16*)take((size_t)NEXP * CDIM * HDIM * 2); //  64 MB  [E][C][H]
  u16*  Hu   = (u16*)take((size_t)SLOTS * HDIM * 2);       // 104 MB
  float* Yu  = (float*)take((size_t)SLOTS * CDIM * 4);     //  52 MB
  float* w01 = (float*)take((size_t)NTOK * 2 * 4);
  int*  e01  = (int*)take((size_t)NTOK * 2 * 4);
  int*  slot_of = (int*)take((size_t)NTOK * 2 * 4);
  int*  order   = (int*)take((size_t)SLOTS * 4);
  int*  tile_expert = (int*)take((size_t)NTILES * 4);
  float* pP  = (float*)take((size_t)RBLK * 8 * 4);         //  32 KB router prob partials
  int*  pC   = (int*)take((size_t)RBLK * 8 * 4);           //  32 KB router count partials
  int*  cursor = (int*)take(256);
  int*  roff   = (int*)take(256);
  size_t need = (size_t)(p - (char*)d_ws);
  if (ws_size < need) return;  // insufficient scratch -> fail visibly (poisoned out)

  // ---- pipeline ----
  init_kernel<<<52, 256, 0, stream>>>(order, tile_expert, cursor);
  xconv_kernel<<<(NTOK * CDIM / 4) / 256, 256, 0, stream>>>(X, Xb);
  tconv_kernel<<<dim3(HDIM / 32, CDIM / 32, 1), 256, 0, stream>>>(sh_w1, W1t, CDIM, HDIM);
  tconv_kernel<<<dim3(CDIM / 32, HDIM / 32, 1), 256, 0, stream>>>(sh_w2, W2t, HDIM, CDIM);
  tconv_kernel<<<dim3(HDIM / 32, CDIM / 32, NEXP), 256, 0, stream>>>(rt_w1, RW1t, CDIM, HDIM);
  tconv_kernel<<<dim3(CDIM / 32, HDIM / 32, NEXP), 256, 0, stream>>>(rt_w2, RW2t, HDIM, CDIM);
  router_kernel<<<RBLK, 256, 0, stream>>>(X, router_w, w01, e01, pP, pC);
  setup_kernel<<<1, 256, 0, stream>>>(pP, pC, roff, tile_expert, out + (size_t)NTOK * CDIM);
  scatter_kernel<<<NTOK / 256, 256, 0, stream>>>(e01, roff, cursor, order, slot_of);
  gemm_h_kernel<<<dim3(HDIM / 128, NTILES), 256, 0, stream>>>(
      Xb, W1t, RW1t, sh_b1, rt_b1, tile_expert, order, Hu);
  gemm_o_kernel<<<dim3(CDIM / 128, NTILES), 256, 0, stream>>>(
      Hu, W2t, RW2t, sh_b2, rt_b2, tile_expert, Yu);
  combine_kernel<<<(NTOK * CDIM / 4) / 256, 256, 0, stream>>>(Yu, w01, slot_of, out);
}